// Round 14
// baseline (803.271 us; speedup 1.0000x reference)
//
#include <hip/hip_runtime.h>
#include <hip/hip_bf16.h>

// ---------------- problem constants ----------------
#define NROWS 32768
#define DIM   512
#define D2    1024
#define KCODE 8192
#define DECAYF 0.99f
#define OMD    0.01f
#define CANDCAP 16
#define ZMAX 6.0f
#define IRANGE 0.04419417382415922f   // 1/sqrt(512)
// int-score margin 0.22 / sfac (3.288e-5) ~= 6691; tile id in low 7 bits
#define MARGIN_P (6700 << 7)

typedef __attribute__((ext_vector_type(4))) int   v4i;
typedef __attribute__((ext_vector_type(16))) int  i32x16;

// ---------------- workspace layout (bytes) ----------------
// emb8t: transposed codebook, per 32-code tile: [64 slots][32 codes][16B] = 32KB
#define WS_EMB8T   0u            // 256 tiles * 32768 = 8,388,608 B
#define WS_YSQ     8388608u      // K int (pre-scaled) = 32,768 B
#define WS_NINT    8421376u      // K int      =     32,768 B
#define WS_ENT     8454144u      // entacc f32 + done-counter int (16 B)
#define WS_FIDX    10682384u     // N int      =    131,072 B
#define WS_OFF     10813456u     // K int      =     32,768 B
#define WS_CUR     10846224u     // K int      =     32,768 B
#define WS_ROWLIST 10878992u     // N int      =    131,072 B

// ---------------- output layout (f32 elements, return order) ----------------
#define OUT_ZQR  0
#define OUT_ZQI  16777216
#define OUT_LOSS 33554432
#define OUT_IDX  33587200
#define OUT_ENT  33619968
#define OUT_NEWW 33619969
#define OUT_NCS  42008577
#define OUT_NEMA 42016769
// pairs scratch: 32768 rows x 128 slots x 8B = 33,554,432 B in the OUT_NEWW
// region (dead until ema_update, which runs after cleanup consumed pairs).
#define PAIRS_OFF (OUT_NEWW + 1)

__device__ __forceinline__ float wredf(float v) {
    #pragma unroll
    for (int o = 32; o > 0; o >>= 1) v += __shfl_down(v, o, 64);
    return v;
}

__device__ __forceinline__ double wredd(double v) {
    #pragma unroll
    for (int o = 32; o > 0; o >>= 1) v += __shfl_down(v, o, 64);
    return __shfl(v, 0, 64);
}

// ULP of float32 at magnitude v (v normal, positive)
__device__ __forceinline__ double ulp32_of(double v) {
    return scalbn(1.0, ilogb(v) - 23);
}

// async global->LDS, 16B per lane; LDS dest = wave-uniform base + lane*16
__device__ __forceinline__ void gload_lds16(const void* g, void* l) {
    __builtin_amdgcn_global_load_lds(
        (const __attribute__((address_space(1))) unsigned int*)(g),
        (__attribute__((address_space(3))) unsigned int*)(l), 16, 0, 0);
}

// quantize 4 floats -> 4 packed i8 (byte0 = x)
__device__ __forceinline__ int q4(float4 v, float s) {
    int a = (int)rintf(fminf(fmaxf(v.x * s, -127.f), 127.f));
    int b = (int)rintf(fminf(fmaxf(v.y * s, -127.f), 127.f));
    int c = (int)rintf(fminf(fmaxf(v.z * s, -127.f), 127.f));
    int d = (int)rintf(fminf(fmaxf(v.w * s, -127.f), 127.f));
    return (a & 255) | ((b & 255) << 8) | ((c & 255) << 16) | ((d & 255) << 24);
}

// ============ 1) y_sq (int grid) + emb -> i8 transposed tiles (+zero nint/ent/cnt) ============
__global__ __launch_bounds__(256) void prep_emb(const float* __restrict__ emb,
                                                char* __restrict__ emb8t,
                                                int* __restrict__ ysq,
                                                int* __restrict__ nint,
                                                float* __restrict__ entacc) {
    // fused init: first 32 blocks zero nint (8192 ints); block 32 zeroes entacc+counter
    if (blockIdx.x < 32) nint[blockIdx.x * 256 + threadIdx.x] = 0;
    else if (blockIdx.x == 32 && threadIdx.x < 4) ((int*)entacc)[threadIdx.x] = 0;

    int wave = threadIdx.x >> 6, lane = threadIdx.x & 63;
    int k = blockIdx.x * 4 + wave;
    const float4* src = (const float4*)(emb + (size_t)k * D2);
    const float es = 127.0f / IRANGE;
    const float sfac_inv = 1.0f / (2.0f * (ZMAX / 127.0f) * (IRANGE / 127.0f));
    float s = 0.f;
    float4 v0 = src[lane * 4 + 0];
    float4 v1 = src[lane * 4 + 1];
    float4 v2 = src[lane * 4 + 2];
    float4 v3 = src[lane * 4 + 3];
    s += v0.x*v0.x + v0.y*v0.y + v0.z*v0.z + v0.w*v0.w;
    s += v1.x*v1.x + v1.y*v1.y + v1.z*v1.z + v1.w*v1.w;
    s += v2.x*v2.x + v2.y*v2.y + v2.z*v2.z + v2.w*v2.w;
    s += v3.x*v3.x + v3.y*v3.y + v3.z*v3.z + v3.w*v3.w;
    v4i pk; pk[0] = q4(v0, es); pk[1] = q4(v1, es); pk[2] = q4(v2, es); pk[3] = q4(v3, es);
    v4i* dst = (v4i*)(emb8t + (size_t)(k >> 5) * 32768 + (size_t)lane * 512 + (k & 31) * 16);
    *dst = pk;
    s = wredf(s);
    if (lane == 0) ysq[k] = (int)rintf(s * sfac_inv);
}

// ============ 2) i8 MFMA approx-score (R9-verified structure, 303 us) — FROZEN ============
// Grid 256 = 128 row-blocks x 2 code-slices, 1 block/CU, 2 waves/SIMD.
// Chunk = 64 codes staged as one 64KB linear copy; double-buffered 2x64KB LDS;
// one barrier per chunk. Conflict-free transposed-tile reads. Packed top-2:
// pk = ((ys - dot) << 7) | tile_id; tv0 = min, tv1 = med3 pattern.
__global__ __launch_bounds__(512, 2) void argmin_gemm(
    const float* __restrict__ zr, const float* __restrict__ zi,
    const char* __restrict__ emb8t, const int* __restrict__ ysq,
    long long* __restrict__ pairs)
{
    __shared__ char bufs[2][65536];
    const int tid  = threadIdx.x;
    const int wave = tid >> 6, lane = tid & 63;
    const int colc = lane & 31;      // A row / B col index
    const int hh   = lane >> 5;      // k-subgroup
    const int rowblk = blockIdx.x >> 1;
    const int slice  = blockIdx.x & 1;

    // ---- A fragments: 32 rows/wave, full K=1024, i8, 128 regs ----
    const int arow = rowblk * 256 + wave * 32 + colc;
    const float zs = 127.0f / ZMAX;
    const float* zrp = zr + (size_t)arow * 512 + hh * 16;
    const float* zip = zi + (size_t)arow * 512 + hh * 16;
    v4i afrag[32];
    #pragma unroll
    for (int ft = 0; ft < 16; ++ft) {
        const float4* p = (const float4*)(zrp + ft * 32);
        v4i a; a[0] = q4(p[0], zs); a[1] = q4(p[1], zs); a[2] = q4(p[2], zs); a[3] = q4(p[3], zs);
        afrag[ft] = a;
    }
    #pragma unroll
    for (int ft = 0; ft < 16; ++ft) {
        const float4* p = (const float4*)(zip + ft * 32);
        v4i a; a[0] = q4(p[0], zs); a[1] = q4(p[1], zs); a[2] = q4(p[2], zs); a[3] = q4(p[3], zs);
        afrag[16 + ft] = a;
    }

    // per-lane per-row top-2 packed scores ((sc<<7)|tile), sorted tv0<=tv1
    int tv0[16], tv1[16];
    #pragma unroll
    for (int g = 0; g < 16; ++g) { tv0[g] = 0x7FFFFFFF; tv1[g] = 0x7FFFFFFF; }

    const char* gslice = emb8t + (size_t)slice * 128 * 32768;
    const int* yslice = ysq + slice * 4096;

    // stage 64-code chunk: 64KB linear copy, 8 x gload16 per wave (8KB/wave)
#define STAGE(dstbuf, c_) do {                                                   \
        const char* gb = gslice + (size_t)(c_) * 65536 + wave * 8192             \
                       + (size_t)lane * 16;                                      \
        char* lb = (dstbuf) + wave * 8192;                                       \
        _Pragma("unroll")                                                        \
        for (int q = 0; q < 8; ++q)                                              \
            gload_lds16(gb + q * 1024, lb + q * 1024);                           \
    } while (0)

    const int boff = colc * 16 + hh * 512;

    STAGE(bufs[0], 0);
    __syncthreads();

    for (int c = 0; c < 64; ++c) {
        const int cur = c & 1;
        if (c + 1 < 64) STAGE(bufs[cur ^ 1], c + 1);
        // ys prefetch at chunk top: latency hides under the MFMA loop
        int ysA = yslice[c * 64 + colc];
        int ysB = yslice[c * 64 + 32 + colc];

        const char* bb = &bufs[cur][0] + boff;
        i32x16 accA, accB;
        #pragma unroll
        for (int g = 0; g < 16; ++g) { accA[g] = 0; accB[g] = 0; }
        __builtin_amdgcn_s_setprio(1);
        #pragma unroll
        for (int m = 0; m < 32; ++m) {
            v4i bA = *(const v4i*)(bb + m * 1024);
            v4i bB = *(const v4i*)(bb + m * 1024 + 32768);
            accA = __builtin_amdgcn_mfma_i32_32x32x32_i8(afrag[m], bA, accA, 0, 0, 0);
            accB = __builtin_amdgcn_mfma_i32_32x32x32_i8(afrag[m], bB, accB, 0, 0, 0);
        }
        __builtin_amdgcn_s_setprio(0);

        const int idA = c * 2, idB = c * 2 + 1;
        #pragma unroll
        for (int g = 0; g < 16; ++g) {
            int pkA = ((ysA - accA[g]) << 7) | idA;
            tv1[g] = min(tv1[g], max(pkA, tv0[g]));   // med3 pattern
            tv0[g] = min(tv0[g], pkA);
            int pkB = ((ysB - accB[g]) << 7) | idB;
            tv1[g] = min(tv1[g], max(pkB, tv0[g]));
            tv0[g] = min(tv0[g], pkB);
        }
        __syncthreads();
    }
#undef STAGE

    // ---- write per-lane top-2 to pair buffer: pairs[row][slice*64 + col*2 + t] ----
    #pragma unroll
    for (int g = 0; g < 16; ++g) {
        int rloc = (g & 3) + 8 * (g >> 2) + 4 * hh;       // C/D row mapping (m74/m101)
        int rowg = rowblk * 256 + wave * 32 + rloc;
        size_t base = (size_t)rowg * 128 + slice * 64 + colc * 2;
        int t0 = tv0[g], t1 = tv1[g];
        int code0 = slice * 4096 + (t0 & 127) * 32 + colc;
        int code1 = slice * 4096 + (t1 & 127) * 32 + colc;
        pairs[base + 0] = ((long long)(unsigned)code0 << 32) | (unsigned)t0;
        pairs[base + 1] = ((long long)(unsigned)code1 << 32) | (unsigned)t1;
    }
}

// ============ 3) fused: merge + numpy-f32 rescore + idx + z_q + loss + hist ============
// One wave per row. Phase 1: min-reduce over the row's 128 packed pairs,
// ballot-compact in-margin candidates into LDS. Phase 2 (cnt>1 only):
// numpy-f32-pipeline rescore: d = fl32(fl32(x_sq+y_sq) - 2*fl32(dot));
// x_sq cancels on its own f32 grid; compare D = G_uS(y) - G_ud(2t),
// ties -> lower index. Phase 3: z_q gather + loss epilogue.
__global__ __launch_bounds__(256) void cleanup(
    const float* __restrict__ zr, const float* __restrict__ zi,
    const float* __restrict__ emb, const long long* __restrict__ pairs,
    int* __restrict__ fidx, int* __restrict__ nint, float* __restrict__ out)
{
    __shared__ int candlds[4][CANDCAP];
    int wave = threadIdx.x >> 6, lane = threadIdx.x & 63;
    int r = blockIdx.x * 4 + wave;

    // ---- phase 1: merge the row's 128 pair slots ----
    const long long* pr = pairs + (size_t)r * 128;
    long long p0 = pr[lane];
    long long p1 = pr[64 + lane];
    int v0v = (int)(unsigned)p0;
    int i0  = (int)(p0 >> 32);
    int v1v = (int)(unsigned)p1;
    int i1  = (int)(p1 >> 32);
    int m = min(v0v, v1v);
    #pragma unroll
    for (int o = 32; o > 0; o >>= 1) m = min(m, __shfl_xor(m, o, 64));
    int lim = m + MARGIN_P;
    unsigned long long m0 = __ballot(v0v < lim);
    unsigned long long m1 = __ballot(v1v < lim);
    int t0 = __popcll(m0);
    int cnt = t0 + __popcll(m1);
    if (cnt > CANDCAP) cnt = CANDCAP;
    unsigned long long below = (lane == 63) ? 0xFFFFFFFFFFFFFFFFull >> 1
                                            : ((1ull << lane) - 1);
    if (v0v < lim) {
        int pos = __popcll(m0 & below);
        if (pos < CANDCAP) candlds[wave][pos] = i0;
    }
    if (v1v < lim) {
        int pos = t0 + __popcll(m1 & below);
        if (pos < CANDCAP) candlds[wave][pos] = i1;
    }
    // within-wave LDS visibility: compiler inserts lgkmcnt wait; no barrier needed
    int best = candlds[wave][0];

    // z row in registers (rescore + epilogue)
    float zreg[16];
    #pragma unroll
    for (int p = 0; p < 4; ++p) {
        int d4 = p * 64 + lane;
        const float4* zp = (d4 < 128) ? (const float4*)(zr + (size_t)r * 512)
                                      : ((const float4*)(zi + (size_t)r * 512) - 128);
        float4 zv = zp[d4];
        zreg[p * 4 + 0] = zv.x; zreg[p * 4 + 1] = zv.y;
        zreg[p * 4 + 2] = zv.z; zreg[p * 4 + 3] = zv.w;
    }

    // ---- phase 2: exact rescore (ambiguous rows only) ----
    if (cnt > 1) {
        double xs = 0.0;
        #pragma unroll
        for (int j = 0; j < 16; ++j) xs += (double)zreg[j] * (double)zreg[j];
        xs = wredd(xs);
        double uS = ulp32_of(xs);

        double bD = 1e300; int bi = 1 << 30;
        for (int i = 0; i < cnt; ++i) {
            int cdx = candlds[wave][i];
            const float4* ep = (const float4*)(emb + (size_t)cdx * 1024);
            double ys = 0.0, tt = 0.0;
            #pragma unroll
            for (int p = 0; p < 4; ++p) {
                float4 ev = ep[p * 64 + lane];
                float q0 = ev.x * ev.x, q1 = ev.y * ev.y, q2 = ev.z * ev.z, q3 = ev.w * ev.w;
                ys += (double)q0 + (double)q1 + (double)q2 + (double)q3;
                tt += (double)zreg[p * 4 + 0] * (double)ev.x
                    + (double)zreg[p * 4 + 1] * (double)ev.y
                    + (double)zreg[p * 4 + 2] * (double)ev.z
                    + (double)zreg[p * 4 + 3] * (double)ev.w;
            }
            ys = wredd(ys);
            tt = wredd(tt);
            float y32 = (float)ys;
            float t32 = (float)tt;
            double dex = xs + ys - 2.0 * tt;
            double ud = ulp32_of(dex);
            double D = rint((double)y32 / uS) * uS - rint(2.0 * (double)t32 / ud) * ud;
            if (D < bD || (D == bD && cdx < bi)) { bD = D; bi = cdx; }
        }
        best = bi;
    }

    // ---- phase 3: z_q gather + loss epilogue ----
    const float4* ep = (const float4*)(emb + (size_t)best * 1024);
    float acc = 0.f;
    #pragma unroll
    for (int p = 0; p < 4; ++p) {
        int d4 = p * 64 + lane;
        float4 ev = ep[d4];
        float dx = ev.x - zreg[p * 4 + 0]; acc += dx * dx;
        float dy = ev.y - zreg[p * 4 + 1]; acc += dy * dy;
        float dz = ev.z - zreg[p * 4 + 2]; acc += dz * dz;
        float dw = ev.w - zreg[p * 4 + 3]; acc += dw * dw;
        float4* op = (d4 < 128) ? (float4*)(out + OUT_ZQR + (size_t)r * 512)
                                : ((float4*)(out + OUT_ZQI + (size_t)r * 512) - 128);
        op[d4] = ev;
    }
    acc = wredf(acc);
    if (lane == 0) {
        fidx[r] = best;
        out[OUT_IDX + r] = (float)best;
        out[OUT_LOSS + r] = 0.25f * acc * (1.f / 1024.f);
        atomicAdd(nint + best, 1);
    }
}

// ============ 4) exclusive prefix sum over K=8192 bucket counts ============
__global__ __launch_bounds__(256) void scan_codes(const int* __restrict__ nint,
                                                  int* __restrict__ off,
                                                  int* __restrict__ cur) {
    __shared__ int part[256];
    int tid = threadIdx.x;
    int base = tid * 32;
    int loc[32];
    int s = 0;
    #pragma unroll
    for (int j = 0; j < 32; ++j) { loc[j] = s; s += nint[base + j]; }
    part[tid] = s;
    __syncthreads();
    for (int o = 1; o < 256; o <<= 1) {
        int t = (tid >= o) ? part[tid - o] : 0;
        __syncthreads();
        part[tid] += t;
        __syncthreads();
    }
    int excl = part[tid] - s;
    #pragma unroll
    for (int j = 0; j < 32; ++j) {
        off[base + j] = excl + loc[j];
        cur[base + j] = 0;
    }
}

// ============ 5) bucket fill: rowlist grouped by assigned code ============
__global__ __launch_bounds__(256) void fill_rows(const int* __restrict__ fidx,
                                                 const int* __restrict__ off,
                                                 int* __restrict__ cur,
                                                 int* __restrict__ rowlist) {
    int r = blockIdx.x * 256 + threadIdx.x;
    int idx = fidx[r];
    int pos = atomicAdd(cur + idx, 1);
    rowlist[off[idx] + pos] = r;
}

// ============ 6) fused EMA tail + entropy finalize: one block per code ============
__global__ __launch_bounds__(256) void ema_update(
    const float* __restrict__ zr, const float* __restrict__ zi,
    const float* __restrict__ emaw, const float* __restrict__ emacs,
    const int* __restrict__ nint, const int* __restrict__ off,
    const int* __restrict__ rowlist, float* __restrict__ out,
    float* __restrict__ entacc)
{
    int k = blockIdx.x;
    int tid = threadIdx.x;
    int cnt = nint[k];
    int o0 = off[k];
    // 2-way unrolled bucket accumulation (ILP on the load+add chain)
    float ax0 = 0.f, ay0 = 0.f, az0 = 0.f, aw0 = 0.f;
    float ax1 = 0.f, ay1 = 0.f, az1 = 0.f, aw1 = 0.f;
    int i = 0;
    for (; i + 1 < cnt; i += 2) {
        int ra = rowlist[o0 + i];
        int rb = rowlist[o0 + i + 1];
        float4 za = (tid < 128) ? ((const float4*)(zr + (size_t)ra * 512))[tid]
                                : ((const float4*)(zi + (size_t)ra * 512))[tid - 128];
        float4 zb = (tid < 128) ? ((const float4*)(zr + (size_t)rb * 512))[tid]
                                : ((const float4*)(zi + (size_t)rb * 512))[tid - 128];
        ax0 += za.x; ay0 += za.y; az0 += za.z; aw0 += za.w;
        ax1 += zb.x; ay1 += zb.y; az1 += zb.z; aw1 += zb.w;
    }
    if (i < cnt) {
        int ra = rowlist[o0 + i];
        float4 za = (tid < 128) ? ((const float4*)(zr + (size_t)ra * 512))[tid]
                                : ((const float4*)(zi + (size_t)ra * 512))[tid - 128];
        ax0 += za.x; ay0 += za.y; az0 += za.z; aw0 += za.w;
    }
    float ax = ax0 + ax1, ay = ay0 + ay1, az = az0 + az1, aw = aw0 + aw1;

    float4 ew = ((const float4*)(emaw + (size_t)k * 1024))[tid];
    float4 nem;
    nem.x = DECAYF * ew.x + OMD * ax;
    nem.y = DECAYF * ew.y + OMD * ay;
    nem.z = DECAYF * ew.z + OMD * az;
    nem.w = DECAYF * ew.w + OMD * aw;
    ((float4*)(out + OUT_NEMA + (size_t)k * 1024))[tid] = nem;
    float ncs = DECAYF * emacs[k] + OMD * (float)cnt;
    float cs = ncs + 1e-5f;
    if (cs < 1.f) cs += 1.f;
    float inv = 1.f / cs;
    float4 w;
    w.x = fminf(fmaxf(nem.x * inv, -5.f), 5.f);
    w.y = fminf(fmaxf(nem.y * inv, -5.f), 5.f);
    w.z = fminf(fmaxf(nem.z * inv, -5.f), 5.f);
    w.w = fminf(fmaxf(nem.w * inv, -5.f), 5.f);
    ((float4*)(out + OUT_NEWW + (size_t)k * 1024))[tid] = w;
    if (tid == 0) {
        out[OUT_NCS + k] = ncs;
        float p = (float)cnt / 32768.f;
        atomicAdd(entacc, -p * logf(p + 1e-10f));
        // fused ent_fin: last block to finish computes the normalized entropy
        __threadfence();
        int* done = (int*)(entacc + 1);
        int old = atomicAdd(done, 1);
        if (old == KCODE - 1) {
            float tot = atomicAdd(entacc, 0.0f);   // coherent read at L2 point
            out[OUT_ENT] = tot / logf(8192.f);
        }
    }
}

// ============ launcher ============
extern "C" void kernel_launch(void* const* d_in, const int* in_sizes, int n_in,
                              void* d_out, int out_size, void* d_ws, size_t ws_size,
                              hipStream_t stream)
{
    const float* zr    = (const float*)d_in[0];
    const float* zi    = (const float*)d_in[1];
    const float* emb   = (const float*)d_in[2];
    const float* emacs = (const float*)d_in[3];
    const float* emaw  = (const float*)d_in[4];
    float* out = (float*)d_out;
    char* ws = (char*)d_ws;

    char*  emb8t   = (char*)(ws + WS_EMB8T);
    int*   ysq     = (int*)(ws + WS_YSQ);
    int*   nint    = (int*)(ws + WS_NINT);
    float* entacc  = (float*)(ws + WS_ENT);
    int*   fidx    = (int*)(ws + WS_FIDX);
    int*   off     = (int*)(ws + WS_OFF);
    int*   cur     = (int*)(ws + WS_CUR);
    int*   rowlist = (int*)(ws + WS_ROWLIST);
    long long* pairs = (long long*)(out + PAIRS_OFF);   // scratch inside new_w region

    prep_emb   <<<2048, 256, 0, stream>>>(emb, emb8t, ysq, nint, entacc);
    argmin_gemm<<<256,  512, 0, stream>>>(zr, zi, emb8t, ysq, pairs);
    cleanup    <<<8192, 256, 0, stream>>>(zr, zi, emb, pairs, fidx, nint, out);
    scan_codes <<<1,    256, 0, stream>>>(nint, off, cur);
    fill_rows  <<<128,  256, 0, stream>>>(fidx, off, cur, rowlist);
    ema_update <<<8192, 256, 0, stream>>>(zr, zi, emaw, emacs, nint, off, rowlist, out, entacc);
}

// Round 15
// 506.770 us; speedup vs baseline: 1.5851x; 1.5851x over previous
//
#include <hip/hip_runtime.h>
#include <hip/hip_bf16.h>

// ---------------- problem constants ----------------
#define NROWS 32768
#define DIM   512
#define D2    1024
#define KCODE 8192
#define DECAYF 0.99f
#define OMD    0.01f
#define CANDCAP 16
#define ZMAX 6.0f
#define IRANGE 0.04419417382415922f   // 1/sqrt(512)
// int-score margin 0.22 / sfac (3.288e-5) ~= 6691; tile id in low 7 bits
#define MARGIN_P (6700 << 7)

typedef __attribute__((ext_vector_type(4))) int   v4i;
typedef __attribute__((ext_vector_type(16))) int  i32x16;

// ---------------- workspace layout (bytes) ----------------
// emb8t: transposed codebook, per 32-code tile: [64 slots][32 codes][16B] = 32KB
#define WS_EMB8T   0u            // 256 tiles * 32768 = 8,388,608 B
#define WS_YSQ     8388608u      // K int (pre-scaled) = 32,768 B
#define WS_NINT    8421376u      // K int      =     32,768 B
#define WS_ENT     8454144u      // entacc f32 (16 B)
#define WS_FIDX    10682384u     // N int      =    131,072 B
#define WS_OFF     10813456u     // K int      =     32,768 B
#define WS_CUR     10846224u     // K int      =     32,768 B
#define WS_ROWLIST 10878992u     // N int      =    131,072 B

// ---------------- output layout (f32 elements, return order) ----------------
#define OUT_ZQR  0
#define OUT_ZQI  16777216
#define OUT_LOSS 33554432
#define OUT_IDX  33587200
#define OUT_ENT  33619968
#define OUT_NEWW 33619969
#define OUT_NCS  42008577
#define OUT_NEMA 42016769
// pairs scratch: 32768 rows x 128 slots x 8B = 33,554,432 B in the OUT_NEWW
// region (dead until ema_update, which runs after cleanup consumed pairs).
#define PAIRS_OFF (OUT_NEWW + 1)

__device__ __forceinline__ float wredf(float v) {
    #pragma unroll
    for (int o = 32; o > 0; o >>= 1) v += __shfl_down(v, o, 64);
    return v;
}

__device__ __forceinline__ double wredd(double v) {
    #pragma unroll
    for (int o = 32; o > 0; o >>= 1) v += __shfl_down(v, o, 64);
    return __shfl(v, 0, 64);
}

// ULP of float32 at magnitude v (v normal, positive)
__device__ __forceinline__ double ulp32_of(double v) {
    return scalbn(1.0, ilogb(v) - 23);
}

// async global->LDS, 16B per lane; LDS dest = wave-uniform base + lane*16
__device__ __forceinline__ void gload_lds16(const void* g, void* l) {
    __builtin_amdgcn_global_load_lds(
        (const __attribute__((address_space(1))) unsigned int*)(g),
        (__attribute__((address_space(3))) unsigned int*)(l), 16, 0, 0);
}

// quantize 4 floats -> 4 packed i8 (byte0 = x)
__device__ __forceinline__ int q4(float4 v, float s) {
    int a = (int)rintf(fminf(fmaxf(v.x * s, -127.f), 127.f));
    int b = (int)rintf(fminf(fmaxf(v.y * s, -127.f), 127.f));
    int c = (int)rintf(fminf(fmaxf(v.z * s, -127.f), 127.f));
    int d = (int)rintf(fminf(fmaxf(v.w * s, -127.f), 127.f));
    return (a & 255) | ((b & 255) << 8) | ((c & 255) << 16) | ((d & 255) << 24);
}

// ============ 1) y_sq (int grid) + emb -> i8 transposed tiles (+zero nint/ent) ============
__global__ __launch_bounds__(256) void prep_emb(const float* __restrict__ emb,
                                                char* __restrict__ emb8t,
                                                int* __restrict__ ysq,
                                                int* __restrict__ nint,
                                                float* __restrict__ entacc) {
    // fused init: first 32 blocks zero nint (8192 ints); block 32 zeroes entacc
    if (blockIdx.x < 32) nint[blockIdx.x * 256 + threadIdx.x] = 0;
    else if (blockIdx.x == 32 && threadIdx.x == 0) entacc[0] = 0.f;

    int wave = threadIdx.x >> 6, lane = threadIdx.x & 63;
    int k = blockIdx.x * 4 + wave;
    const float4* src = (const float4*)(emb + (size_t)k * D2);
    const float es = 127.0f / IRANGE;
    const float sfac_inv = 1.0f / (2.0f * (ZMAX / 127.0f) * (IRANGE / 127.0f));
    float s = 0.f;
    float4 v0 = src[lane * 4 + 0];
    float4 v1 = src[lane * 4 + 1];
    float4 v2 = src[lane * 4 + 2];
    float4 v3 = src[lane * 4 + 3];
    s += v0.x*v0.x + v0.y*v0.y + v0.z*v0.z + v0.w*v0.w;
    s += v1.x*v1.x + v1.y*v1.y + v1.z*v1.z + v1.w*v1.w;
    s += v2.x*v2.x + v2.y*v2.y + v2.z*v2.z + v2.w*v2.w;
    s += v3.x*v3.x + v3.y*v3.y + v3.z*v3.z + v3.w*v3.w;
    v4i pk; pk[0] = q4(v0, es); pk[1] = q4(v1, es); pk[2] = q4(v2, es); pk[3] = q4(v3, es);
    v4i* dst = (v4i*)(emb8t + (size_t)(k >> 5) * 32768 + (size_t)lane * 512 + (k & 31) * 16);
    *dst = pk;
    s = wredf(s);
    if (lane == 0) ysq[k] = (int)rintf(s * sfac_inv);
}

// ============ 2) i8 MFMA approx-score (R9-verified structure, 303 us) — FROZEN ============
// Grid 256 = 128 row-blocks x 2 code-slices, 1 block/CU, 2 waves/SIMD.
// Chunk = 64 codes staged as one 64KB linear copy; double-buffered 2x64KB LDS;
// one barrier per chunk. Conflict-free transposed-tile reads. Packed top-2:
// pk = ((ys - dot) << 7) | tile_id; tv0 = min, tv1 = med3 pattern.
__global__ __launch_bounds__(512, 2) void argmin_gemm(
    const float* __restrict__ zr, const float* __restrict__ zi,
    const char* __restrict__ emb8t, const int* __restrict__ ysq,
    long long* __restrict__ pairs)
{
    __shared__ char bufs[2][65536];
    const int tid  = threadIdx.x;
    const int wave = tid >> 6, lane = tid & 63;
    const int colc = lane & 31;      // A row / B col index
    const int hh   = lane >> 5;      // k-subgroup
    const int rowblk = blockIdx.x >> 1;
    const int slice  = blockIdx.x & 1;

    // ---- A fragments: 32 rows/wave, full K=1024, i8, 128 regs ----
    const int arow = rowblk * 256 + wave * 32 + colc;
    const float zs = 127.0f / ZMAX;
    const float* zrp = zr + (size_t)arow * 512 + hh * 16;
    const float* zip = zi + (size_t)arow * 512 + hh * 16;
    v4i afrag[32];
    #pragma unroll
    for (int ft = 0; ft < 16; ++ft) {
        const float4* p = (const float4*)(zrp + ft * 32);
        v4i a; a[0] = q4(p[0], zs); a[1] = q4(p[1], zs); a[2] = q4(p[2], zs); a[3] = q4(p[3], zs);
        afrag[ft] = a;
    }
    #pragma unroll
    for (int ft = 0; ft < 16; ++ft) {
        const float4* p = (const float4*)(zip + ft * 32);
        v4i a; a[0] = q4(p[0], zs); a[1] = q4(p[1], zs); a[2] = q4(p[2], zs); a[3] = q4(p[3], zs);
        afrag[16 + ft] = a;
    }

    // per-lane per-row top-2 packed scores ((sc<<7)|tile), sorted tv0<=tv1
    int tv0[16], tv1[16];
    #pragma unroll
    for (int g = 0; g < 16; ++g) { tv0[g] = 0x7FFFFFFF; tv1[g] = 0x7FFFFFFF; }

    const char* gslice = emb8t + (size_t)slice * 128 * 32768;
    const int* yslice = ysq + slice * 4096;

    // stage 64-code chunk: 64KB linear copy, 8 x gload16 per wave (8KB/wave)
#define STAGE(dstbuf, c_) do {                                                   \
        const char* gb = gslice + (size_t)(c_) * 65536 + wave * 8192             \
                       + (size_t)lane * 16;                                      \
        char* lb = (dstbuf) + wave * 8192;                                       \
        _Pragma("unroll")                                                        \
        for (int q = 0; q < 8; ++q)                                              \
            gload_lds16(gb + q * 1024, lb + q * 1024);                           \
    } while (0)

    const int boff = colc * 16 + hh * 512;

    STAGE(bufs[0], 0);
    __syncthreads();

    for (int c = 0; c < 64; ++c) {
        const int cur = c & 1;
        if (c + 1 < 64) STAGE(bufs[cur ^ 1], c + 1);
        // ys prefetch at chunk top: latency hides under the MFMA loop
        int ysA = yslice[c * 64 + colc];
        int ysB = yslice[c * 64 + 32 + colc];

        const char* bb = &bufs[cur][0] + boff;
        i32x16 accA, accB;
        #pragma unroll
        for (int g = 0; g < 16; ++g) { accA[g] = 0; accB[g] = 0; }
        __builtin_amdgcn_s_setprio(1);
        #pragma unroll
        for (int m = 0; m < 32; ++m) {
            v4i bA = *(const v4i*)(bb + m * 1024);
            v4i bB = *(const v4i*)(bb + m * 1024 + 32768);
            accA = __builtin_amdgcn_mfma_i32_32x32x32_i8(afrag[m], bA, accA, 0, 0, 0);
            accB = __builtin_amdgcn_mfma_i32_32x32x32_i8(afrag[m], bB, accB, 0, 0, 0);
        }
        __builtin_amdgcn_s_setprio(0);

        const int idA = c * 2, idB = c * 2 + 1;
        #pragma unroll
        for (int g = 0; g < 16; ++g) {
            int pkA = ((ysA - accA[g]) << 7) | idA;
            tv1[g] = min(tv1[g], max(pkA, tv0[g]));   // med3 pattern
            tv0[g] = min(tv0[g], pkA);
            int pkB = ((ysB - accB[g]) << 7) | idB;
            tv1[g] = min(tv1[g], max(pkB, tv0[g]));
            tv0[g] = min(tv0[g], pkB);
        }
        __syncthreads();
    }
#undef STAGE

    // ---- write per-lane top-2 to pair buffer: pairs[row][slice*64 + col*2 + t] ----
    #pragma unroll
    for (int g = 0; g < 16; ++g) {
        int rloc = (g & 3) + 8 * (g >> 2) + 4 * hh;       // C/D row mapping (m74/m101)
        int rowg = rowblk * 256 + wave * 32 + rloc;
        size_t base = (size_t)rowg * 128 + slice * 64 + colc * 2;
        int t0 = tv0[g], t1 = tv1[g];
        int code0 = slice * 4096 + (t0 & 127) * 32 + colc;
        int code1 = slice * 4096 + (t1 & 127) * 32 + colc;
        pairs[base + 0] = ((long long)(unsigned)code0 << 32) | (unsigned)t0;
        pairs[base + 1] = ((long long)(unsigned)code1 << 32) | (unsigned)t1;
    }
}

// ============ 3) fused: merge + numpy-f32 rescore + idx + z_q + loss + hist ============
// One wave per row. Phase 1: min-reduce over the row's 128 packed pairs,
// ballot-compact in-margin candidates into LDS. Phase 2 (cnt>1 only):
// numpy-f32-pipeline rescore: d = fl32(fl32(x_sq+y_sq) - 2*fl32(dot));
// x_sq cancels on its own f32 grid; compare D = G_uS(y) - G_ud(2t),
// ties -> lower index. Phase 3: z_q gather + loss epilogue.
__global__ __launch_bounds__(256) void cleanup(
    const float* __restrict__ zr, const float* __restrict__ zi,
    const float* __restrict__ emb, const long long* __restrict__ pairs,
    int* __restrict__ fidx, int* __restrict__ nint, float* __restrict__ out)
{
    __shared__ int candlds[4][CANDCAP];
    int wave = threadIdx.x >> 6, lane = threadIdx.x & 63;
    int r = blockIdx.x * 4 + wave;

    // ---- phase 1: merge the row's 128 pair slots ----
    const long long* pr = pairs + (size_t)r * 128;
    long long p0 = pr[lane];
    long long p1 = pr[64 + lane];
    int v0v = (int)(unsigned)p0;
    int i0  = (int)(p0 >> 32);
    int v1v = (int)(unsigned)p1;
    int i1  = (int)(p1 >> 32);
    int m = min(v0v, v1v);
    #pragma unroll
    for (int o = 32; o > 0; o >>= 1) m = min(m, __shfl_xor(m, o, 64));
    int lim = m + MARGIN_P;
    unsigned long long m0 = __ballot(v0v < lim);
    unsigned long long m1 = __ballot(v1v < lim);
    int t0 = __popcll(m0);
    int cnt = t0 + __popcll(m1);
    if (cnt > CANDCAP) cnt = CANDCAP;
    unsigned long long below = (lane == 63) ? 0xFFFFFFFFFFFFFFFFull >> 1
                                            : ((1ull << lane) - 1);
    if (v0v < lim) {
        int pos = __popcll(m0 & below);
        if (pos < CANDCAP) candlds[wave][pos] = i0;
    }
    if (v1v < lim) {
        int pos = t0 + __popcll(m1 & below);
        if (pos < CANDCAP) candlds[wave][pos] = i1;
    }
    // within-wave LDS visibility: compiler inserts lgkmcnt wait; no barrier needed
    int best = candlds[wave][0];

    // z row in registers (rescore + epilogue)
    float zreg[16];
    #pragma unroll
    for (int p = 0; p < 4; ++p) {
        int d4 = p * 64 + lane;
        const float4* zp = (d4 < 128) ? (const float4*)(zr + (size_t)r * 512)
                                      : ((const float4*)(zi + (size_t)r * 512) - 128);
        float4 zv = zp[d4];
        zreg[p * 4 + 0] = zv.x; zreg[p * 4 + 1] = zv.y;
        zreg[p * 4 + 2] = zv.z; zreg[p * 4 + 3] = zv.w;
    }

    // ---- phase 2: exact rescore (ambiguous rows only) ----
    if (cnt > 1) {
        double xs = 0.0;
        #pragma unroll
        for (int j = 0; j < 16; ++j) xs += (double)zreg[j] * (double)zreg[j];
        xs = wredd(xs);
        double uS = ulp32_of(xs);

        double bD = 1e300; int bi = 1 << 30;
        for (int i = 0; i < cnt; ++i) {
            int cdx = candlds[wave][i];
            const float4* ep = (const float4*)(emb + (size_t)cdx * 1024);
            double ys = 0.0, tt = 0.0;
            #pragma unroll
            for (int p = 0; p < 4; ++p) {
                float4 ev = ep[p * 64 + lane];
                float q0 = ev.x * ev.x, q1 = ev.y * ev.y, q2 = ev.z * ev.z, q3 = ev.w * ev.w;
                ys += (double)q0 + (double)q1 + (double)q2 + (double)q3;
                tt += (double)zreg[p * 4 + 0] * (double)ev.x
                    + (double)zreg[p * 4 + 1] * (double)ev.y
                    + (double)zreg[p * 4 + 2] * (double)ev.z
                    + (double)zreg[p * 4 + 3] * (double)ev.w;
            }
            ys = wredd(ys);
            tt = wredd(tt);
            float y32 = (float)ys;
            float t32 = (float)tt;
            double dex = xs + ys - 2.0 * tt;
            double ud = ulp32_of(dex);
            double D = rint((double)y32 / uS) * uS - rint(2.0 * (double)t32 / ud) * ud;
            if (D < bD || (D == bD && cdx < bi)) { bD = D; bi = cdx; }
        }
        best = bi;
    }

    // ---- phase 3: z_q gather + loss epilogue ----
    const float4* ep = (const float4*)(emb + (size_t)best * 1024);
    float acc = 0.f;
    #pragma unroll
    for (int p = 0; p < 4; ++p) {
        int d4 = p * 64 + lane;
        float4 ev = ep[d4];
        float dx = ev.x - zreg[p * 4 + 0]; acc += dx * dx;
        float dy = ev.y - zreg[p * 4 + 1]; acc += dy * dy;
        float dz = ev.z - zreg[p * 4 + 2]; acc += dz * dz;
        float dw = ev.w - zreg[p * 4 + 3]; acc += dw * dw;
        float4* op = (d4 < 128) ? (float4*)(out + OUT_ZQR + (size_t)r * 512)
                                : ((float4*)(out + OUT_ZQI + (size_t)r * 512) - 128);
        op[d4] = ev;
    }
    acc = wredf(acc);
    if (lane == 0) {
        fidx[r] = best;
        out[OUT_IDX + r] = (float)best;
        out[OUT_LOSS + r] = 0.25f * acc * (1.f / 1024.f);
        atomicAdd(nint + best, 1);
    }
}

// ============ 4) exclusive prefix sum over K=8192 bucket counts ============
__global__ __launch_bounds__(256) void scan_codes(const int* __restrict__ nint,
                                                  int* __restrict__ off,
                                                  int* __restrict__ cur) {
    __shared__ int part[256];
    int tid = threadIdx.x;
    int base = tid * 32;
    int loc[32];
    int s = 0;
    #pragma unroll
    for (int j = 0; j < 32; ++j) { loc[j] = s; s += nint[base + j]; }
    part[tid] = s;
    __syncthreads();
    for (int o = 1; o < 256; o <<= 1) {
        int t = (tid >= o) ? part[tid - o] : 0;
        __syncthreads();
        part[tid] += t;
        __syncthreads();
    }
    int excl = part[tid] - s;
    #pragma unroll
    for (int j = 0; j < 32; ++j) {
        off[base + j] = excl + loc[j];
        cur[base + j] = 0;
    }
}

// ============ 5) bucket fill: rowlist grouped by assigned code ============
__global__ __launch_bounds__(256) void fill_rows(const int* __restrict__ fidx,
                                                 const int* __restrict__ off,
                                                 int* __restrict__ cur,
                                                 int* __restrict__ rowlist) {
    int r = blockIdx.x * 256 + threadIdx.x;
    int idx = fidx[r];
    int pos = atomicAdd(cur + idx, 1);
    rowlist[off[idx] + pos] = r;
}

// ============ 6) fused EMA tail: one block per code (R13-verified form) ============
__global__ __launch_bounds__(256) void ema_update(
    const float* __restrict__ zr, const float* __restrict__ zi,
    const float* __restrict__ emaw, const float* __restrict__ emacs,
    const int* __restrict__ nint, const int* __restrict__ off,
    const int* __restrict__ rowlist, float* __restrict__ out,
    float* __restrict__ entacc)
{
    int k = blockIdx.x;
    int tid = threadIdx.x;
    int cnt = nint[k];
    int o0 = off[k];
    float ax = 0.f, ay = 0.f, az = 0.f, aw = 0.f;
    for (int i = 0; i < cnt; ++i) {
        int r = rowlist[o0 + i];
        float4 zv = (tid < 128) ? ((const float4*)(zr + (size_t)r * 512))[tid]
                                : ((const float4*)(zi + (size_t)r * 512))[tid - 128];
        ax += zv.x; ay += zv.y; az += zv.z; aw += zv.w;
    }
    float4 ew = ((const float4*)(emaw + (size_t)k * 1024))[tid];
    float4 nem;
    nem.x = DECAYF * ew.x + OMD * ax;
    nem.y = DECAYF * ew.y + OMD * ay;
    nem.z = DECAYF * ew.z + OMD * az;
    nem.w = DECAYF * ew.w + OMD * aw;
    ((float4*)(out + OUT_NEMA + (size_t)k * 1024))[tid] = nem;
    float ncs = DECAYF * emacs[k] + OMD * (float)cnt;
    float cs = ncs + 1e-5f;
    if (cs < 1.f) cs += 1.f;
    float inv = 1.f / cs;
    float4 w;
    w.x = fminf(fmaxf(nem.x * inv, -5.f), 5.f);
    w.y = fminf(fmaxf(nem.y * inv, -5.f), 5.f);
    w.z = fminf(fmaxf(nem.z * inv, -5.f), 5.f);
    w.w = fminf(fmaxf(nem.w * inv, -5.f), 5.f);
    ((float4*)(out + OUT_NEWW + (size_t)k * 1024))[tid] = w;
    if (tid == 0) {
        out[OUT_NCS + k] = ncs;
        float p = (float)cnt / 32768.f;
        atomicAdd(entacc, -p * logf(p + 1e-10f));
    }
}

__global__ void ent_fin(const float* __restrict__ entacc, float* __restrict__ out) {
    if (threadIdx.x == 0) out[OUT_ENT] = entacc[0] / logf(8192.f);
}

// ============ launcher ============
extern "C" void kernel_launch(void* const* d_in, const int* in_sizes, int n_in,
                              void* d_out, int out_size, void* d_ws, size_t ws_size,
                              hipStream_t stream)
{
    const float* zr    = (const float*)d_in[0];
    const float* zi    = (const float*)d_in[1];
    const float* emb   = (const float*)d_in[2];
    const float* emacs = (const float*)d_in[3];
    const float* emaw  = (const float*)d_in[4];
    float* out = (float*)d_out;
    char* ws = (char*)d_ws;

    char*  emb8t   = (char*)(ws + WS_EMB8T);
    int*   ysq     = (int*)(ws + WS_YSQ);
    int*   nint    = (int*)(ws + WS_NINT);
    float* entacc  = (float*)(ws + WS_ENT);
    int*   fidx    = (int*)(ws + WS_FIDX);
    int*   off     = (int*)(ws + WS_OFF);
    int*   cur     = (int*)(ws + WS_CUR);
    int*   rowlist = (int*)(ws + WS_ROWLIST);
    long long* pairs = (long long*)(out + PAIRS_OFF);   // scratch inside new_w region

    prep_emb   <<<2048, 256, 0, stream>>>(emb, emb8t, ysq, nint, entacc);
    argmin_gemm<<<256,  512, 0, stream>>>(zr, zi, emb8t, ysq, pairs);
    cleanup    <<<8192, 256, 0, stream>>>(zr, zi, emb, pairs, fidx, nint, out);
    scan_codes <<<1,    256, 0, stream>>>(nint, off, cur);
    fill_rows  <<<128,  256, 0, stream>>>(fidx, off, cur, rowlist);
    ema_update <<<8192, 256, 0, stream>>>(zr, zi, emaw, emacs, nint, off, rowlist, out, entacc);
    ent_fin    <<<1,    64,  0, stream>>>(entacc, out);
}